// Round 3
// baseline (17780.374 us; speedup 1.0000x reference)
//
#include <hip/hip_runtime.h>
#include <math.h>

// MetaNETS Langevin sampler, MI355X — round 3.
// Round-2 lesson: __launch_bounds__(256,4) => 64-VGPR cap => acc arrays spilled
// to scratch (FETCH 3.9GB, WRITE 619MB of pure spill traffic). Fix: bounds
// (256,2) + 16-acc x 2 half-passes per wave (pass loop pinned with unroll 1)
// so natural VGPR use ~100-120, no spills, occupancy still 4 blocks/CU (LDS).

#define B_TOT 2048
#define NPT   64
#define ZD    64
#define HD    128

__device__ __forceinline__ float sigf(float x) {
  return __builtin_amdgcn_rcpf(1.0f + __expf(-x));
}

__device__ __forceinline__ unsigned int packbf(float a, float b) {
  unsigned int ua = __float_as_uint(a);
  unsigned int ub = __float_as_uint(b);
  ua += 0x7FFFu + ((ua >> 16) & 1u);   // RNE bf16 rounding
  ub += 0x7FFFu + ((ub >> 16) & 1u);
  return (ua >> 16) | (ub & 0xFFFF0000u);
}

__device__ __forceinline__ float wsum64(float v) {
  #pragma unroll
  for (int d = 1; d < 64; d <<= 1) v += __shfl_xor(v, d, 64);
  return v;
}

__global__ void prep_kernel(const float* __restrict__ Wd1, const float* __restrict__ Wd2,
                            float* __restrict__ Wd2T, float* __restrict__ Wd1zT) {
  const int i = blockIdx.x * 256 + threadIdx.x;
  if (i < 128 * 128) {
    const int k = i >> 7, h = i & 127;
    Wd2T[h * 128 + k] = Wd2[k * 128 + h];
  }
  if (i < 64 * 128) {
    const int j = i >> 7, k = i & 127;
    Wd1zT[k * 64 + j] = Wd1[j * 128 + k];
  }
}

__global__ __launch_bounds__(256, 2)
void metanets_kernel(
    const float* __restrict__ x_ctx, const float* __restrict__ y_ctx,
    const float* __restrict__ mask,  const float* __restrict__ z0,
    const float* __restrict__ noises,
    const float* __restrict__ We1, const float* __restrict__ be1,
    const float* __restrict__ We2, const float* __restrict__ be2,
    const float* __restrict__ We3, const float* __restrict__ be3,
    const float* __restrict__ Wd1, const float* __restrict__ bd1,
    const float* __restrict__ Wd2, const float* __restrict__ bd2,
    const float* __restrict__ Wd3, const float* __restrict__ bd3,
    const float* __restrict__ Wf1, const float* __restrict__ bf1,
    const float* __restrict__ Wf2, const float* __restrict__ bf2,
    const float* __restrict__ Wf3, const float* __restrict__ bf3,
    const float* __restrict__ Wd2T, const float* __restrict__ Wd1zT,
    float* __restrict__ out, int steps, float dt, float dco)
{
  __shared__ float h1pf[64 * 64];   // packed bf16 pairs [k/2][point]
  __shared__ float taupf[64 * 64];  // packed bf16 pairs [h/2][point]
  __shared__ float zsh[64];
  __shared__ float zw1[128];
  __shared__ float rsh[128];
  __shared__ float dsum[128];
  __shared__ float f1sh[128];
  __shared__ float f2sh[128];
  __shared__ float eacc[4 * 64];    // per-wave dacc partials [w][point]
  __shared__ float bgz[128];        // drift-out | gz partials

  const int tid  = threadIdx.x;
  const int lane = tid & 63;                                  // context point
  const int w    = __builtin_amdgcn_readfirstlane(tid >> 6);  // wave id (SGPR)
  const int b    = blockIdx.x;

  const float x0v = x_ctx[(b * NPT + lane) * 2 + 0];
  const float x1v = x_ctx[(b * NPT + lane) * 2 + 1];
  const float yv  = y_ctx[b * NPT + lane];
  const float mk  = mask[b * NPT + lane];
  const float inv_msum = 1.0f / fmaxf(wsum64(mk), 1e-6f);

  if (tid < 64) zsh[tid] = z0[b * ZD + tid];
  __syncthreads();

  const int h0 = 32 * w;   // this wave's 32-wide h-range (fwd) / k-range (bwd)

  // ---------------- encoder: r = meanpool(MLP([x,y])) ----------------
  {
    for (int k2 = 16 * w; k2 < 16 * w + 16; ++k2) {
      const int ka = 2 * k2, kb = 2 * k2 + 1;
      const float sA = be1[ka] + x0v * We1[0 * HD + ka] + x1v * We1[1 * HD + ka]
                               + yv  * We1[2 * HD + ka];
      const float sB = be1[kb] + x0v * We1[0 * HD + kb] + x1v * We1[1 * HD + kb]
                               + yv  * We1[2 * HD + kb];
      h1pf[k2 * 64 + lane] = __uint_as_float(packbf(sA * sigf(sA), sB * sigf(sB)));
    }
    __syncthreads();

    #pragma unroll 1
    for (int p = 0; p < 2; ++p) {               // layer 2, 16 cols per pass
      const int c0 = h0 + 16 * p;
      float acc[16];
      #pragma unroll
      for (int i = 0; i < 16; ++i) acc[i] = be2[c0 + i];
      for (int k2 = 0; k2 < 64; ++k2) {
        const unsigned int wd = __float_as_uint(h1pf[k2 * 64 + lane]);
        const float a0 = __uint_as_float(wd << 16);
        const float a1 = __uint_as_float(wd & 0xFFFF0000u);
        #pragma unroll
        for (int i = 0; i < 16; ++i) {
          acc[i] = fmaf(a0, We2[(2 * k2) * HD + c0 + i], acc[i]);
          acc[i] = fmaf(a1, We2[(2 * k2 + 1) * HD + c0 + i], acc[i]);
        }
      }
      #pragma unroll
      for (int i = 0; i < 16; i += 2) {
        const float v0 = acc[i] * sigf(acc[i]);
        const float v1 = acc[i + 1] * sigf(acc[i + 1]);
        taupf[(c0 + i) / 2 * 64 + lane] = __uint_as_float(packbf(v0, v1));
      }
    }
    __syncthreads();

    #pragma unroll 1
    for (int p = 0; p < 2; ++p) {               // layer 3 -> masked mean -> rsh
      const int c0 = h0 + 16 * p;
      float acc[16];
      #pragma unroll
      for (int i = 0; i < 16; ++i) acc[i] = be3[c0 + i];
      for (int k2 = 0; k2 < 64; ++k2) {
        const unsigned int wd = __float_as_uint(taupf[k2 * 64 + lane]);
        const float a0 = __uint_as_float(wd << 16);
        const float a1 = __uint_as_float(wd & 0xFFFF0000u);
        #pragma unroll
        for (int i = 0; i < 16; ++i) {
          acc[i] = fmaf(a0, We3[(2 * k2) * HD + c0 + i], acc[i]);
          acc[i] = fmaf(a1, We3[(2 * k2 + 1) * HD + c0 + i], acc[i]);
        }
      }
      #pragma unroll
      for (int i = 0; i < 16; ++i) {
        const float v = wsum64(acc[i] * mk);
        if (lane == 0) rsh[c0 + i] = v * inv_msum;
      }
    }
    __syncthreads();
  }

  // ---------------- Langevin step loop ----------------
  for (int st = 0; st < steps; ++st) {
    const float t = (float)st * dt;

    // zW1[k] = bd1[k] + sum_j z[j] Wd1[j,k]   (4-way ILP)
    if (tid < 128) {
      float p0 = bd1[tid], p1 = 0.0f, p2 = 0.0f, p3 = 0.0f;
      for (int j = 0; j < 64; j += 4) {
        p0 = fmaf(zsh[j + 0], Wd1[(j + 0) * HD + tid], p0);
        p1 = fmaf(zsh[j + 1], Wd1[(j + 1) * HD + tid], p1);
        p2 = fmaf(zsh[j + 2], Wd1[(j + 2) * HD + tid], p2);
        p3 = fmaf(zsh[j + 3], Wd1[(j + 3) * HD + tid], p3);
      }
      zw1[tid] = (p0 + p1) + (p2 + p3);
    }
    __syncthreads();

    // decoder layer 1: wave w writes packed words [16w,16w+16)
    for (int k2 = 16 * w; k2 < 16 * w + 16; ++k2) {
      const int ka = 2 * k2, kb = 2 * k2 + 1;
      const float sA = zw1[ka] + x0v * Wd1[64 * HD + ka] + x1v * Wd1[65 * HD + ka];
      const float sB = zw1[kb] + x0v * Wd1[64 * HD + kb] + x1v * Wd1[65 * HD + kb];
      h1pf[k2 * 64 + lane] = __uint_as_float(packbf(sA * sigf(sA), sB * sigf(sB)));
    }
    __syncthreads();

    // decoder layer 2+3 forward; emit tau + per-wave dacc partial
    {
      float dacc_w = 0.0f;
      #pragma unroll 1
      for (int p = 0; p < 2; ++p) {
        const int c0 = h0 + 16 * p;
        float acc[16];
        #pragma unroll
        for (int i = 0; i < 16; ++i) acc[i] = bd2[c0 + i];
        for (int k2 = 0; k2 < 64; ++k2) {
          const unsigned int wd = __float_as_uint(h1pf[k2 * 64 + lane]);
          const float a0 = __uint_as_float(wd << 16);
          const float a1 = __uint_as_float(wd & 0xFFFF0000u);
          #pragma unroll
          for (int i = 0; i < 16; ++i) {
            acc[i] = fmaf(a0, Wd2[(2 * k2) * HD + c0 + i], acc[i]);
            acc[i] = fmaf(a1, Wd2[(2 * k2 + 1) * HD + c0 + i], acc[i]);
          }
        }
        #pragma unroll
        for (int i = 0; i < 16; i += 2) {
          const float s2a = acc[i], s2b = acc[i + 1];
          const float sga = sigf(s2a), sgb = sigf(s2b);
          const float w3a = Wd3[c0 + i], w3b = Wd3[c0 + i + 1];
          dacc_w = fmaf(s2a * sga, w3a, dacc_w);
          dacc_w = fmaf(s2b * sgb, w3b, dacc_w);
          const float tva = w3a * (sga * fmaf(s2a, 1.0f - sga, 1.0f));
          const float tvb = w3b * (sgb * fmaf(s2b, 1.0f - sgb, 1.0f));
          taupf[(c0 + i) / 2 * 64 + lane] = __uint_as_float(packbf(tva, tvb));
        }
      }
      eacc[w * 64 + lane] = dacc_w;
    }
    __syncthreads();

    const float dacc = bd3[0] + eacc[lane] + eacc[64 + lane]
                              + eacc[128 + lane] + eacc[192 + lane];
    const float ebw = t * mk * (dacc - yv);   // t and mask folded into e

    // backward: u = Wd2T-slice @ tau; dsum[k] = colsum over points of delta1
    #pragma unroll 1
    for (int p = 0; p < 2; ++p) {
      const int c0 = h0 + 16 * p;
      float u[16];
      #pragma unroll
      for (int i = 0; i < 16; ++i) u[i] = 0.0f;
      for (int h2 = 0; h2 < 64; ++h2) {
        const unsigned int wd = __float_as_uint(taupf[h2 * 64 + lane]);
        const float t0 = __uint_as_float(wd << 16);
        const float t1 = __uint_as_float(wd & 0xFFFF0000u);
        #pragma unroll
        for (int i = 0; i < 16; ++i) {
          u[i] = fmaf(t0, Wd2T[(2 * h2) * HD + c0 + i], u[i]);
          u[i] = fmaf(t1, Wd2T[(2 * h2 + 1) * HD + c0 + i], u[i]);
        }
      }
      #pragma unroll
      for (int i = 0; i < 16; ++i) {
        const int k = c0 + i;
        const float s1 = zw1[k] + x0v * Wd1[64 * HD + k] + x1v * Wd1[65 * HD + k];
        const float sg = sigf(s1);
        const float d1 = ebw * (sg * fmaf(s1, 1.0f - sg, 1.0f)) * u[i];
        const float v = wsum64(d1);
        if (lane == 0) dsum[k] = v;
      }
    }
    __syncthreads();

    // drift MLP: [z, r, t] -> 128 -> 128 -> 64   (4-way ILP dot products)
    if (tid < 128) {
      float p0 = fmaf(t, Wf1[192 * HD + tid], bf1[tid]);
      float p1 = 0.0f, p2 = 0.0f, p3 = 0.0f;
      for (int j = 0; j < 64; j += 4) {
        p0 = fmaf(zsh[j + 0], Wf1[(j + 0) * HD + tid], p0);
        p1 = fmaf(zsh[j + 1], Wf1[(j + 1) * HD + tid], p1);
        p2 = fmaf(zsh[j + 2], Wf1[(j + 2) * HD + tid], p2);
        p3 = fmaf(zsh[j + 3], Wf1[(j + 3) * HD + tid], p3);
      }
      for (int j = 0; j < 128; j += 4) {
        p0 = fmaf(rsh[j + 0], Wf1[(64 + j + 0) * HD + tid], p0);
        p1 = fmaf(rsh[j + 1], Wf1[(64 + j + 1) * HD + tid], p1);
        p2 = fmaf(rsh[j + 2], Wf1[(64 + j + 2) * HD + tid], p2);
        p3 = fmaf(rsh[j + 3], Wf1[(64 + j + 3) * HD + tid], p3);
      }
      const float a = (p0 + p1) + (p2 + p3);
      f1sh[tid] = a * sigf(a);
    }
    __syncthreads();
    if (tid < 128) {
      float p0 = bf2[tid], p1 = 0.0f, p2 = 0.0f, p3 = 0.0f;
      for (int j = 0; j < 128; j += 4) {
        p0 = fmaf(f1sh[j + 0], Wf2[(j + 0) * HD + tid], p0);
        p1 = fmaf(f1sh[j + 1], Wf2[(j + 1) * HD + tid], p1);
        p2 = fmaf(f1sh[j + 2], Wf2[(j + 2) * HD + tid], p2);
        p3 = fmaf(f1sh[j + 3], Wf2[(j + 3) * HD + tid], p3);
      }
      const float a = (p0 + p1) + (p2 + p3);
      f2sh[tid] = a * sigf(a);
    }
    __syncthreads();
    if (tid < 128) {
      if (tid < 64) {
        float p0 = bf3[tid], p1 = 0.0f, p2 = 0.0f, p3 = 0.0f;
        for (int h = 0; h < 128; h += 4) {
          p0 = fmaf(f2sh[h + 0], Wf3[(h + 0) * ZD + tid], p0);
          p1 = fmaf(f2sh[h + 1], Wf3[(h + 1) * ZD + tid], p1);
          p2 = fmaf(f2sh[h + 2], Wf3[(h + 2) * ZD + tid], p2);
          p3 = fmaf(f2sh[h + 3], Wf3[(h + 3) * ZD + tid], p3);
        }
        bgz[tid] = (p0 + p1) + (p2 + p3);          // drift output b_j
      } else {
        const int j = tid - 64;
        float p0 = 0.0f, p1 = 0.0f, p2 = 0.0f, p3 = 0.0f;
        for (int h = 0; h < 128; h += 4) {
          p0 = fmaf(dsum[h + 0], Wd1zT[(h + 0) * ZD + j], p0);
          p1 = fmaf(dsum[h + 1], Wd1zT[(h + 1) * ZD + j], p1);
          p2 = fmaf(dsum[h + 2], Wd1zT[(h + 2) * ZD + j], p2);
          p3 = fmaf(dsum[h + 3], Wd1zT[(h + 3) * ZD + j], p3);
        }
        bgz[64 + j] = (p0 + p1) + (p2 + p3);       // gz_j (t already in ebw)
      }
    }
    __syncthreads();
    if (tid < 64) {
      const float zold = zsh[tid];
      float g = zold + bgz[64 + tid];
      g = fminf(fmaxf(g, -100.0f), 100.0f);
      zsh[tid] = zold + (bgz[tid] - g) * dt
               + dco * noises[(size_t)st * (B_TOT * ZD) + b * ZD + tid];
    }
    __syncthreads();
  }

  if (tid < 64) out[b * ZD + tid] = zsh[tid];
}

extern "C" void kernel_launch(void* const* d_in, const int* in_sizes, int n_in,
                              void* d_out, int out_size, void* d_ws, size_t ws_size,
                              hipStream_t stream) {
  const float* x_ctx  = (const float*)d_in[0];
  const float* y_ctx  = (const float*)d_in[1];
  const float* mask   = (const float*)d_in[2];
  const float* z0     = (const float*)d_in[3];
  const float* noises = (const float*)d_in[4];
  const float* We1 = (const float*)d_in[5];  const float* be1 = (const float*)d_in[6];
  const float* We2 = (const float*)d_in[7];  const float* be2 = (const float*)d_in[8];
  const float* We3 = (const float*)d_in[9];  const float* be3 = (const float*)d_in[10];
  const float* Wd1 = (const float*)d_in[11]; const float* bd1 = (const float*)d_in[12];
  const float* Wd2 = (const float*)d_in[13]; const float* bd2 = (const float*)d_in[14];
  const float* Wd3 = (const float*)d_in[15]; const float* bd3 = (const float*)d_in[16];
  const float* Wf1 = (const float*)d_in[17]; const float* bf1 = (const float*)d_in[18];
  const float* Wf2 = (const float*)d_in[19]; const float* bf2 = (const float*)d_in[20];
  const float* Wf3 = (const float*)d_in[21]; const float* bf3 = (const float*)d_in[22];

  const int steps = in_sizes[4] / (B_TOT * ZD);
  const float dt  = 1.0f / (float)steps;
  const float dco = (float)sqrt(2.0 / (double)steps);

  float* Wd2T  = (float*)d_ws;            // 128x128
  float* Wd1zT = Wd2T + 128 * 128;        // 128x64

  hipLaunchKernelGGL(prep_kernel, dim3(64), dim3(256), 0, stream, Wd1, Wd2, Wd2T, Wd1zT);
  hipLaunchKernelGGL(metanets_kernel, dim3(B_TOT), dim3(256), 0, stream,
      x_ctx, y_ctx, mask, z0, noises,
      We1, be1, We2, be2, We3, be3,
      Wd1, bd1, Wd2, bd2, Wd3, bd3,
      Wf1, bf1, Wf2, bf2, Wf3, bf3,
      Wd2T, Wd1zT, (float*)d_out, steps, dt, dco);
}

// Round 4
// 5189.081 us; speedup vs baseline: 3.4265x; 3.4265x over previous
//
#include <hip/hip_runtime.h>
#include <math.h>

// MetaNETS Langevin sampler, MI355X — round 4.
// R2/R3 lesson: backend targets 4 waves/EU (128-VGPR budget) regardless of
// launch_bounds min; 16-acc GEMM passes need ~160-190 VGPR naturally -> spill
// (WRITE 2.2GB of scratch, FETCH 9GB L2-thrash). Fix: 8-acc x 4 passes per
// wave + "#pragma unroll 4" on inner k-loops so natural demand ~<=110 VGPR
// fits the 128 budget with NO spill. LDS 37KB -> 4 blocks/CU -> 16 waves/CU.

#define B_TOT 2048
#define NPT   64
#define ZD    64
#define HD    128

__device__ __forceinline__ float sigf(float x) {
  return __builtin_amdgcn_rcpf(1.0f + __expf(-x));
}

__device__ __forceinline__ unsigned int packbf(float a, float b) {
  unsigned int ua = __float_as_uint(a);
  unsigned int ub = __float_as_uint(b);
  ua += 0x7FFFu + ((ua >> 16) & 1u);   // RNE bf16 rounding
  ub += 0x7FFFu + ((ub >> 16) & 1u);
  return (ua >> 16) | (ub & 0xFFFF0000u);
}

__device__ __forceinline__ float wsum64(float v) {
  #pragma unroll
  for (int d = 1; d < 64; d <<= 1) v += __shfl_xor(v, d, 64);
  return v;
}

__global__ void prep_kernel(const float* __restrict__ Wd1, const float* __restrict__ Wd2,
                            float* __restrict__ Wd2T, float* __restrict__ Wd1zT) {
  const int i = blockIdx.x * 256 + threadIdx.x;
  if (i < 128 * 128) {
    const int k = i >> 7, h = i & 127;
    Wd2T[h * 128 + k] = Wd2[k * 128 + h];
  }
  if (i < 64 * 128) {
    const int j = i >> 7, k = i & 127;
    Wd1zT[k * 64 + j] = Wd1[j * 128 + k];
  }
}

__global__ __launch_bounds__(256, 2)
void metanets_kernel(
    const float* __restrict__ x_ctx, const float* __restrict__ y_ctx,
    const float* __restrict__ mask,  const float* __restrict__ z0,
    const float* __restrict__ noises,
    const float* __restrict__ We1, const float* __restrict__ be1,
    const float* __restrict__ We2, const float* __restrict__ be2,
    const float* __restrict__ We3, const float* __restrict__ be3,
    const float* __restrict__ Wd1, const float* __restrict__ bd1,
    const float* __restrict__ Wd2, const float* __restrict__ bd2,
    const float* __restrict__ Wd3, const float* __restrict__ bd3,
    const float* __restrict__ Wf1, const float* __restrict__ bf1,
    const float* __restrict__ Wf2, const float* __restrict__ bf2,
    const float* __restrict__ Wf3, const float* __restrict__ bf3,
    const float* __restrict__ Wd2T, const float* __restrict__ Wd1zT,
    float* __restrict__ out, int steps, float dt, float dco)
{
  __shared__ float h1pf[64 * 64];   // packed bf16 pairs [k/2][point]
  __shared__ float taupf[64 * 64];  // packed bf16 pairs [h/2][point]
  __shared__ float zsh[64];
  __shared__ float zw1[128];
  __shared__ float rsh[128];
  __shared__ float dsum[128];
  __shared__ float f1sh[128];
  __shared__ float f2sh[128];
  __shared__ float eacc[4 * 64];    // per-wave dacc partials [w][point]
  __shared__ float bgz[128];        // drift-out | gz partials

  const int tid  = threadIdx.x;
  const int lane = tid & 63;                                  // context point
  const int w    = __builtin_amdgcn_readfirstlane(tid >> 6);  // wave id (SGPR)
  const int b    = blockIdx.x;

  const float x0v = x_ctx[(b * NPT + lane) * 2 + 0];
  const float x1v = x_ctx[(b * NPT + lane) * 2 + 1];
  const float yv  = y_ctx[b * NPT + lane];
  const float mk  = mask[b * NPT + lane];
  const float inv_msum = 1.0f / fmaxf(wsum64(mk), 1e-6f);

  if (tid < 64) zsh[tid] = z0[b * ZD + tid];
  __syncthreads();

  const int h0 = 32 * w;   // this wave's 32-wide h-range (fwd) / k-range (bwd)

  // ---------------- encoder: r = meanpool(MLP([x,y])) ----------------
  {
    for (int k2 = 16 * w; k2 < 16 * w + 16; ++k2) {
      const int ka = 2 * k2, kb = 2 * k2 + 1;
      const float sA = be1[ka] + x0v * We1[0 * HD + ka] + x1v * We1[1 * HD + ka]
                               + yv  * We1[2 * HD + ka];
      const float sB = be1[kb] + x0v * We1[0 * HD + kb] + x1v * We1[1 * HD + kb]
                               + yv  * We1[2 * HD + kb];
      h1pf[k2 * 64 + lane] = __uint_as_float(packbf(sA * sigf(sA), sB * sigf(sB)));
    }
    __syncthreads();

    #pragma unroll 1
    for (int p = 0; p < 4; ++p) {               // layer 2, 8 cols per pass
      const int c0 = h0 + 8 * p;
      float acc[8];
      #pragma unroll
      for (int i = 0; i < 8; ++i) acc[i] = be2[c0 + i];
      #pragma unroll 4
      for (int k2 = 0; k2 < 64; ++k2) {
        const unsigned int wd = __float_as_uint(h1pf[k2 * 64 + lane]);
        const float a0 = __uint_as_float(wd << 16);
        const float a1 = __uint_as_float(wd & 0xFFFF0000u);
        #pragma unroll
        for (int i = 0; i < 8; ++i) {
          acc[i] = fmaf(a0, We2[(2 * k2) * HD + c0 + i], acc[i]);
          acc[i] = fmaf(a1, We2[(2 * k2 + 1) * HD + c0 + i], acc[i]);
        }
      }
      #pragma unroll
      for (int i = 0; i < 8; i += 2) {
        const float v0 = acc[i] * sigf(acc[i]);
        const float v1 = acc[i + 1] * sigf(acc[i + 1]);
        taupf[(c0 + i) / 2 * 64 + lane] = __uint_as_float(packbf(v0, v1));
      }
    }
    __syncthreads();

    #pragma unroll 1
    for (int p = 0; p < 4; ++p) {               // layer 3 -> masked mean -> rsh
      const int c0 = h0 + 8 * p;
      float acc[8];
      #pragma unroll
      for (int i = 0; i < 8; ++i) acc[i] = be3[c0 + i];
      #pragma unroll 4
      for (int k2 = 0; k2 < 64; ++k2) {
        const unsigned int wd = __float_as_uint(taupf[k2 * 64 + lane]);
        const float a0 = __uint_as_float(wd << 16);
        const float a1 = __uint_as_float(wd & 0xFFFF0000u);
        #pragma unroll
        for (int i = 0; i < 8; ++i) {
          acc[i] = fmaf(a0, We3[(2 * k2) * HD + c0 + i], acc[i]);
          acc[i] = fmaf(a1, We3[(2 * k2 + 1) * HD + c0 + i], acc[i]);
        }
      }
      #pragma unroll
      for (int i = 0; i < 8; ++i) {
        const float v = wsum64(acc[i] * mk);
        if (lane == 0) rsh[c0 + i] = v * inv_msum;
      }
    }
    __syncthreads();
  }

  // ---------------- Langevin step loop ----------------
  for (int st = 0; st < steps; ++st) {
    const float t = (float)st * dt;

    // zW1[k] = bd1[k] + sum_j z[j] Wd1[j,k]   (4-way ILP)
    if (tid < 128) {
      float p0 = bd1[tid], p1 = 0.0f, p2 = 0.0f, p3 = 0.0f;
      #pragma unroll 4
      for (int j = 0; j < 64; j += 4) {
        p0 = fmaf(zsh[j + 0], Wd1[(j + 0) * HD + tid], p0);
        p1 = fmaf(zsh[j + 1], Wd1[(j + 1) * HD + tid], p1);
        p2 = fmaf(zsh[j + 2], Wd1[(j + 2) * HD + tid], p2);
        p3 = fmaf(zsh[j + 3], Wd1[(j + 3) * HD + tid], p3);
      }
      zw1[tid] = (p0 + p1) + (p2 + p3);
    }
    __syncthreads();

    // decoder layer 1: wave w writes packed words [16w,16w+16)
    for (int k2 = 16 * w; k2 < 16 * w + 16; ++k2) {
      const int ka = 2 * k2, kb = 2 * k2 + 1;
      const float sA = zw1[ka] + x0v * Wd1[64 * HD + ka] + x1v * Wd1[65 * HD + ka];
      const float sB = zw1[kb] + x0v * Wd1[64 * HD + kb] + x1v * Wd1[65 * HD + kb];
      h1pf[k2 * 64 + lane] = __uint_as_float(packbf(sA * sigf(sA), sB * sigf(sB)));
    }
    __syncthreads();

    // decoder layer 2+3 forward; emit tau + per-wave dacc partial
    {
      float dacc_w = 0.0f;
      #pragma unroll 1
      for (int p = 0; p < 4; ++p) {
        const int c0 = h0 + 8 * p;
        float acc[8];
        #pragma unroll
        for (int i = 0; i < 8; ++i) acc[i] = bd2[c0 + i];
        #pragma unroll 4
        for (int k2 = 0; k2 < 64; ++k2) {
          const unsigned int wd = __float_as_uint(h1pf[k2 * 64 + lane]);
          const float a0 = __uint_as_float(wd << 16);
          const float a1 = __uint_as_float(wd & 0xFFFF0000u);
          #pragma unroll
          for (int i = 0; i < 8; ++i) {
            acc[i] = fmaf(a0, Wd2[(2 * k2) * HD + c0 + i], acc[i]);
            acc[i] = fmaf(a1, Wd2[(2 * k2 + 1) * HD + c0 + i], acc[i]);
          }
        }
        #pragma unroll
        for (int i = 0; i < 8; i += 2) {
          const float s2a = acc[i], s2b = acc[i + 1];
          const float sga = sigf(s2a), sgb = sigf(s2b);
          const float w3a = Wd3[c0 + i], w3b = Wd3[c0 + i + 1];
          dacc_w = fmaf(s2a * sga, w3a, dacc_w);
          dacc_w = fmaf(s2b * sgb, w3b, dacc_w);
          const float tva = w3a * (sga * fmaf(s2a, 1.0f - sga, 1.0f));
          const float tvb = w3b * (sgb * fmaf(s2b, 1.0f - sgb, 1.0f));
          taupf[(c0 + i) / 2 * 64 + lane] = __uint_as_float(packbf(tva, tvb));
        }
      }
      eacc[w * 64 + lane] = dacc_w;
    }
    __syncthreads();

    const float dacc = bd3[0] + eacc[lane] + eacc[64 + lane]
                              + eacc[128 + lane] + eacc[192 + lane];
    const float ebw = t * mk * (dacc - yv);   // t and mask folded into e

    // backward: u = Wd2T-slice @ tau; dsum[k] = colsum over points of delta1
    #pragma unroll 1
    for (int p = 0; p < 4; ++p) {
      const int c0 = h0 + 8 * p;
      float u[8];
      #pragma unroll
      for (int i = 0; i < 8; ++i) u[i] = 0.0f;
      #pragma unroll 4
      for (int h2 = 0; h2 < 64; ++h2) {
        const unsigned int wd = __float_as_uint(taupf[h2 * 64 + lane]);
        const float t0 = __uint_as_float(wd << 16);
        const float t1 = __uint_as_float(wd & 0xFFFF0000u);
        #pragma unroll
        for (int i = 0; i < 8; ++i) {
          u[i] = fmaf(t0, Wd2T[(2 * h2) * HD + c0 + i], u[i]);
          u[i] = fmaf(t1, Wd2T[(2 * h2 + 1) * HD + c0 + i], u[i]);
        }
      }
      #pragma unroll
      for (int i = 0; i < 8; ++i) {
        const int k = c0 + i;
        const float s1 = zw1[k] + x0v * Wd1[64 * HD + k] + x1v * Wd1[65 * HD + k];
        const float sg = sigf(s1);
        const float d1 = ebw * (sg * fmaf(s1, 1.0f - sg, 1.0f)) * u[i];
        const float v = wsum64(d1);
        if (lane == 0) dsum[k] = v;
      }
    }
    __syncthreads();

    // drift MLP: [z, r, t] -> 128 -> 128 -> 64   (4-way ILP dot products)
    if (tid < 128) {
      float p0 = fmaf(t, Wf1[192 * HD + tid], bf1[tid]);
      float p1 = 0.0f, p2 = 0.0f, p3 = 0.0f;
      #pragma unroll 4
      for (int j = 0; j < 64; j += 4) {
        p0 = fmaf(zsh[j + 0], Wf1[(j + 0) * HD + tid], p0);
        p1 = fmaf(zsh[j + 1], Wf1[(j + 1) * HD + tid], p1);
        p2 = fmaf(zsh[j + 2], Wf1[(j + 2) * HD + tid], p2);
        p3 = fmaf(zsh[j + 3], Wf1[(j + 3) * HD + tid], p3);
      }
      #pragma unroll 4
      for (int j = 0; j < 128; j += 4) {
        p0 = fmaf(rsh[j + 0], Wf1[(64 + j + 0) * HD + tid], p0);
        p1 = fmaf(rsh[j + 1], Wf1[(64 + j + 1) * HD + tid], p1);
        p2 = fmaf(rsh[j + 2], Wf1[(64 + j + 2) * HD + tid], p2);
        p3 = fmaf(rsh[j + 3], Wf1[(64 + j + 3) * HD + tid], p3);
      }
      const float a = (p0 + p1) + (p2 + p3);
      f1sh[tid] = a * sigf(a);
    }
    __syncthreads();
    if (tid < 128) {
      float p0 = bf2[tid], p1 = 0.0f, p2 = 0.0f, p3 = 0.0f;
      #pragma unroll 4
      for (int j = 0; j < 128; j += 4) {
        p0 = fmaf(f1sh[j + 0], Wf2[(j + 0) * HD + tid], p0);
        p1 = fmaf(f1sh[j + 1], Wf2[(j + 1) * HD + tid], p1);
        p2 = fmaf(f1sh[j + 2], Wf2[(j + 2) * HD + tid], p2);
        p3 = fmaf(f1sh[j + 3], Wf2[(j + 3) * HD + tid], p3);
      }
      const float a = (p0 + p1) + (p2 + p3);
      f2sh[tid] = a * sigf(a);
    }
    __syncthreads();
    if (tid < 128) {
      if (tid < 64) {
        float p0 = bf3[tid], p1 = 0.0f, p2 = 0.0f, p3 = 0.0f;
        #pragma unroll 4
        for (int h = 0; h < 128; h += 4) {
          p0 = fmaf(f2sh[h + 0], Wf3[(h + 0) * ZD + tid], p0);
          p1 = fmaf(f2sh[h + 1], Wf3[(h + 1) * ZD + tid], p1);
          p2 = fmaf(f2sh[h + 2], Wf3[(h + 2) * ZD + tid], p2);
          p3 = fmaf(f2sh[h + 3], Wf3[(h + 3) * ZD + tid], p3);
        }
        bgz[tid] = (p0 + p1) + (p2 + p3);          // drift output b_j
      } else {
        const int j = tid - 64;
        float p0 = 0.0f, p1 = 0.0f, p2 = 0.0f, p3 = 0.0f;
        #pragma unroll 4
        for (int h = 0; h < 128; h += 4) {
          p0 = fmaf(dsum[h + 0], Wd1zT[(h + 0) * ZD + j], p0);
          p1 = fmaf(dsum[h + 1], Wd1zT[(h + 1) * ZD + j], p1);
          p2 = fmaf(dsum[h + 2], Wd1zT[(h + 2) * ZD + j], p2);
          p3 = fmaf(dsum[h + 3], Wd1zT[(h + 3) * ZD + j], p3);
        }
        bgz[64 + j] = (p0 + p1) + (p2 + p3);       // gz_j (t already in ebw)
      }
    }
    __syncthreads();
    if (tid < 64) {
      const float zold = zsh[tid];
      float g = zold + bgz[64 + tid];
      g = fminf(fmaxf(g, -100.0f), 100.0f);
      zsh[tid] = zold + (bgz[tid] - g) * dt
               + dco * noises[(size_t)st * (B_TOT * ZD) + b * ZD + tid];
    }
    __syncthreads();
  }

  if (tid < 64) out[b * ZD + tid] = zsh[tid];
}

extern "C" void kernel_launch(void* const* d_in, const int* in_sizes, int n_in,
                              void* d_out, int out_size, void* d_ws, size_t ws_size,
                              hipStream_t stream) {
  const float* x_ctx  = (const float*)d_in[0];
  const float* y_ctx  = (const float*)d_in[1];
  const float* mask   = (const float*)d_in[2];
  const float* z0     = (const float*)d_in[3];
  const float* noises = (const float*)d_in[4];
  const float* We1 = (const float*)d_in[5];  const float* be1 = (const float*)d_in[6];
  const float* We2 = (const float*)d_in[7];  const float* be2 = (const float*)d_in[8];
  const float* We3 = (const float*)d_in[9];  const float* be3 = (const float*)d_in[10];
  const float* Wd1 = (const float*)d_in[11]; const float* bd1 = (const float*)d_in[12];
  const float* Wd2 = (const float*)d_in[13]; const float* bd2 = (const float*)d_in[14];
  const float* Wd3 = (const float*)d_in[15]; const float* bd3 = (const float*)d_in[16];
  const float* Wf1 = (const float*)d_in[17]; const float* bf1 = (const float*)d_in[18];
  const float* Wf2 = (const float*)d_in[19]; const float* bf2 = (const float*)d_in[20];
  const float* Wf3 = (const float*)d_in[21]; const float* bf3 = (const float*)d_in[22];

  const int steps = in_sizes[4] / (B_TOT * ZD);
  const float dt  = 1.0f / (float)steps;
  const float dco = (float)sqrt(2.0 / (double)steps);

  float* Wd2T  = (float*)d_ws;            // 128x128
  float* Wd1zT = Wd2T + 128 * 128;        // 128x64

  hipLaunchKernelGGL(prep_kernel, dim3(64), dim3(256), 0, stream, Wd1, Wd2, Wd2T, Wd1zT);
  hipLaunchKernelGGL(metanets_kernel, dim3(B_TOT), dim3(256), 0, stream,
      x_ctx, y_ctx, mask, z0, noises,
      We1, be1, We2, be2, We3, be3,
      Wd1, bd1, Wd2, bd2, Wd3, bd3,
      Wf1, bf1, Wf2, bf2, Wf3, bf3,
      Wd2T, Wd1zT, (float*)d_out, steps, dt, dco);
}

// Round 5
// 1195.508 us; speedup vs baseline: 14.8726x; 4.3405x over previous
//
#include <hip/hip_runtime.h>
#include <math.h>

// MetaNETS Langevin sampler, MI355X — round 5: MFMA for the big GEMMs.
// Per block (batch elem), 4 waves; wave w owns m-tile w (points 16w..16w+15).
// fwd S2 = H1[64x128] @ Wd2[128x128] and bwd U = TAU @ Wd2^T via
// mfma_f32_16x16x32_bf16 (32 MFMA each per wave). Activations in LDS in
// A-frag-contiguous layout (ds_read_b128); weights as prep-swizzled bf16
// B-frag arrays in d_ws (L2-resident). tau is written C->A layout by a
// pair-shfl ds_write_b32 scatter; all fwd->bwd data is m-tile-local so no
// barrier between them. Encoder L2/L3 use the same MFMA machinery.
// launch_bounds(256,1): do NOT let the allocator force 128-VGPR spills (R3).

#define B_TOT 2048
#define NPT   64
#define ZD    64
#define HD    128

typedef short bh8 __attribute__((ext_vector_type(8)));   // 8 x bf16 (4 VGPR)
typedef float fx4 __attribute__((ext_vector_type(4)));   // MFMA C/D

__device__ __forceinline__ float sigf(float x) {
  return __builtin_amdgcn_rcpf(1.0f + __expf(-x));
}
__device__ __forceinline__ unsigned int bfb(float x) {   // fp32 -> bf16 bits (RNE)
  unsigned int u = __float_as_uint(x);
  u += 0x7FFFu + ((u >> 16) & 1u);
  return u >> 16;
}
__device__ __forceinline__ unsigned int packbf(float a, float b) {
  unsigned int ua = __float_as_uint(a), ub = __float_as_uint(b);
  ua += 0x7FFFu + ((ua >> 16) & 1u);
  ub += 0x7FFFu + ((ub >> 16) & 1u);
  return (ua >> 16) | (ub & 0xFFFF0000u);
}
__device__ __forceinline__ float wsum64(float v) {
  #pragma unroll
  for (int d = 1; d < 64; d <<= 1) v += __shfl_xor(v, d, 64);
  return v;
}
__device__ __forceinline__ void wave_sync() {   // intra-wave LDS order + drain
  __builtin_amdgcn_wave_barrier();
  __builtin_amdgcn_s_waitcnt(0xC07F);           // lgkmcnt(0)
  __builtin_amdgcn_wave_barrier();
}

// B-frag arrays (bf16): for W[K=128][N=128] with K = contraction:
//   frag[((kc*8+nt)*64 + L)*8 + j] = W[kc*32 + (L>>4)*8 + j][nt*16 + (L&15)]
// arr0: Wd2 (fwd)   arr1: Wd2^T (bwd)   arr2: We2   arr3: We3
__global__ __launch_bounds__(256)
void prep_kernel(const float* __restrict__ Wd2, const float* __restrict__ We2,
                 const float* __restrict__ We3, ushort* __restrict__ ws) {
  const int id = blockIdx.x * 256 + threadIdx.x;   // 65536 total
  const int arr = id >> 14;
  const int e = id & 16383;
  const int j = e & 7, L = (e >> 3) & 63, nt = (e >> 9) & 7, kc = e >> 12;
  const int kk = kc * 32 + (L >> 4) * 8 + j, nn = nt * 16 + (L & 15);
  float v;
  if      (arr == 0) v = Wd2[kk * HD + nn];
  else if (arr == 1) v = Wd2[nn * HD + kk];    // Wd2^T
  else if (arr == 2) v = We2[kk * HD + nn];
  else               v = We3[kk * HD + nn];
  ws[id] = (ushort)bfb(v);
}

__global__ __launch_bounds__(256, 1)
void metanets_kernel(
    const float* __restrict__ x_ctx, const float* __restrict__ y_ctx,
    const float* __restrict__ mask,  const float* __restrict__ z0,
    const float* __restrict__ noises,
    const float* __restrict__ We1, const float* __restrict__ be1,
    const float* __restrict__ be2, const float* __restrict__ be3,
    const float* __restrict__ Wd1, const float* __restrict__ bd1,
    const float* __restrict__ bd2, const float* __restrict__ Wd3,
    const float* __restrict__ bd3,
    const float* __restrict__ Wf1, const float* __restrict__ bf1,
    const float* __restrict__ Wf2, const float* __restrict__ bf2,
    const float* __restrict__ Wf3, const float* __restrict__ bf3,
    const ushort* __restrict__ wsfrag,
    float* __restrict__ out, int steps, float dt, float dco)
{
  __shared__ unsigned int h1f[4096];    // A-frag units: [(kc*4+mt)*64 + lane] x 4 dw
  __shared__ unsigned int tauf[4096];
  __shared__ float zsh[64];
  __shared__ float zw1[128];
  __shared__ float rsh[128];
  __shared__ float dsumP[512];
  __shared__ float dsumC[128];
  __shared__ float f1sh[128];           // be2 staging, then drift hidden1
  __shared__ float f2sh[128];           // be3 staging, then drift hidden2
  __shared__ float bgz[128];
  __shared__ float bd2sh[128], wd3sh[128], wx0sh[128], wx1sh[128];

  const int tid = threadIdx.x;
  const int lane = tid & 63;                                  // context point
  const int w = __builtin_amdgcn_readfirstlane(tid >> 6);     // wave = m-tile
  const int b = blockIdx.x;
  const int rr = lane & 15, qq = lane >> 4;

  const bh8* Wd2f  = (const bh8*)(wsfrag);
  const bh8* Wd2Tf = (const bh8*)(wsfrag + 16384);
  const bh8* We2f  = (const bh8*)(wsfrag + 32768);
  const bh8* We3f  = (const bh8*)(wsfrag + 49152);

  const float x0v = x_ctx[(b*NPT + lane)*2 + 0];
  const float x1v = x_ctx[(b*NPT + lane)*2 + 1];
  const float yv  = y_ctx[b*NPT + lane];
  const float mkv = mask[b*NPT + lane];
  const float inv_msum = 1.0f / fmaxf(wsum64(mkv), 1e-6f);
  const float bd3v = bd3[0];

  // per-lane data for the 4 C-rows this lane holds (points 16w+4*qq+g)
  float x0q[4], x1q[4], yq[4], mkq[4];
  #pragma unroll
  for (int g = 0; g < 4; ++g) {
    const int src = (w << 4) | (qq << 2) | g;
    x0q[g] = __shfl(x0v, src, 64);
    x1q[g] = __shfl(x1v, src, 64);
    yq[g]  = __shfl(yv,  src, 64);
    mkq[g] = __shfl(mkv, src, 64);
  }

  if (tid < 64) zsh[tid] = z0[b*ZD + tid];
  if (tid < 128) {
    bd2sh[tid] = bd2[tid];
    wd3sh[tid] = Wd3[tid];
    wx0sh[tid] = Wd1[64*HD + tid];
    wx1sh[tid] = Wd1[65*HD + tid];
    f1sh[tid]  = be2[tid];
    f2sh[tid]  = be3[tid];
  }
  __syncthreads();

  // ================= encoder =================
  // enc L1: lane=point, wave w computes k-slice kc=w, writes A-frag layout
  #pragma unroll
  for (int quad = 0; quad < 4; ++quad) {
    unsigned int pw[4];
    #pragma unroll
    for (int jj = 0; jj < 8; jj += 2) {
      const int k = 32*w + 8*quad + jj;
      const float sA = be1[k]   + x0v*We1[k]   + x1v*We1[HD+k]   + yv*We1[2*HD+k];
      const float sB = be1[k+1] + x0v*We1[k+1] + x1v*We1[HD+k+1] + yv*We1[2*HD+k+1];
      pw[jj>>1] = packbf(sA*sigf(sA), sB*sigf(sB));
    }
    uint4 v4; v4.x = pw[0]; v4.y = pw[1]; v4.z = pw[2]; v4.w = pw[3];
    ((uint4*)h1f)[(w*4 + (lane>>4))*64 + quad*16 + (lane&15)] = v4;
  }
  __syncthreads();

  // enc L2 (MFMA): H2 = silu(H1 @ We2 + be2) -> tauf (A-frag layout)
  {
    bh8 af[4];
    #pragma unroll
    for (int kc = 0; kc < 4; ++kc)
      af[kc] = ((const bh8*)h1f)[(kc*4 + w)*64 + lane];
    #pragma unroll 1
    for (int half = 0; half < 2; ++half) {
      const int h4 = half*4;
      fx4 acc[4];
      #pragma unroll
      for (int i = 0; i < 4; ++i) {
        const float bv = f1sh[(h4+i)*16 + rr];
        acc[i] = (fx4){bv, bv, bv, bv};
      }
      #pragma unroll
      for (int i = 0; i < 4; ++i) {
        const int nt = h4 + i;
        const bh8 b0 = We2f[(0*8+nt)*64 + lane];
        const bh8 b1 = We2f[(1*8+nt)*64 + lane];
        const bh8 b2 = We2f[(2*8+nt)*64 + lane];
        const bh8 b3 = We2f[(3*8+nt)*64 + lane];
        acc[i] = __builtin_amdgcn_mfma_f32_16x16x32_bf16(af[0], b0, acc[i], 0,0,0);
        acc[i] = __builtin_amdgcn_mfma_f32_16x16x32_bf16(af[1], b1, acc[i], 0,0,0);
        acc[i] = __builtin_amdgcn_mfma_f32_16x16x32_bf16(af[2], b2, acc[i], 0,0,0);
        acc[i] = __builtin_amdgcn_mfma_f32_16x16x32_bf16(af[3], b3, acc[i], 0,0,0);
      }
      #pragma unroll
      for (int i = 0; i < 4; ++i) {
        const int nt = h4 + i;
        #pragma unroll
        for (int g = 0; g < 4; ++g) {
          const float s2 = acc[i][g];
          const unsigned int tb = bfb(s2 * sigf(s2));
          const unsigned int pb = (unsigned int)__shfl_xor((int)tb, 1, 64);
          if ((rr & 1) == 0) {
            const int unit = ((nt>>1)*4 + w)*64 + (2*(nt&1) + (rr>>3))*16 + 4*qq + g;
            tauf[unit*4 + ((rr&7)>>1)] = tb | (pb << 16);
          }
        }
      }
    }
  }
  wave_sync();

  // enc L3 (MFMA) + masked mean-pool -> rsh
  {
    bh8 tf4[4];
    #pragma unroll
    for (int kc = 0; kc < 4; ++kc)
      tf4[kc] = ((const bh8*)tauf)[(kc*4 + w)*64 + lane];
    #pragma unroll 1
    for (int half = 0; half < 2; ++half) {
      const int h4 = half*4;
      fx4 acc[4];
      #pragma unroll
      for (int i = 0; i < 4; ++i) {
        const float bv = f2sh[(h4+i)*16 + rr];
        acc[i] = (fx4){bv, bv, bv, bv};
      }
      #pragma unroll
      for (int i = 0; i < 4; ++i) {
        const int nt = h4 + i;
        const bh8 b0 = We3f[(0*8+nt)*64 + lane];
        const bh8 b1 = We3f[(1*8+nt)*64 + lane];
        const bh8 b2 = We3f[(2*8+nt)*64 + lane];
        const bh8 b3 = We3f[(3*8+nt)*64 + lane];
        acc[i] = __builtin_amdgcn_mfma_f32_16x16x32_bf16(tf4[0], b0, acc[i], 0,0,0);
        acc[i] = __builtin_amdgcn_mfma_f32_16x16x32_bf16(tf4[1], b1, acc[i], 0,0,0);
        acc[i] = __builtin_amdgcn_mfma_f32_16x16x32_bf16(tf4[2], b2, acc[i], 0,0,0);
        acc[i] = __builtin_amdgcn_mfma_f32_16x16x32_bf16(tf4[3], b3, acc[i], 0,0,0);
      }
      #pragma unroll
      for (int i = 0; i < 4; ++i) {
        float pv = mkq[0]*acc[i][0] + mkq[1]*acc[i][1]
                 + mkq[2]*acc[i][2] + mkq[3]*acc[i][3];
        pv += __shfl_xor(pv, 16, 64);
        pv += __shfl_xor(pv, 32, 64);
        if (lane < 16) dsumP[w*128 + (h4+i)*16 + lane] = pv;
      }
    }
  }
  __syncthreads();
  if (tid < 128)
    rsh[tid] = (dsumP[tid] + dsumP[128+tid] + dsumP[256+tid] + dsumP[384+tid]) * inv_msum;
  __syncthreads();

  // ================= Langevin step loop =================
  for (int st = 0; st < steps; ++st) {
    const float t = (float)st * dt;

    // zW1[k] = bd1[k] + sum_j z[j] Wd1[j,k]
    if (tid < 128) {
      float p0 = bd1[tid], p1 = 0.f, p2 = 0.f, p3 = 0.f;
      #pragma unroll 4
      for (int j = 0; j < 64; j += 4) {
        p0 = fmaf(zsh[j+0], Wd1[(j+0)*HD + tid], p0);
        p1 = fmaf(zsh[j+1], Wd1[(j+1)*HD + tid], p1);
        p2 = fmaf(zsh[j+2], Wd1[(j+2)*HD + tid], p2);
        p3 = fmaf(zsh[j+3], Wd1[(j+3)*HD + tid], p3);
      }
      zw1[tid] = (p0+p1) + (p2+p3);
    }
    __syncthreads();

    // dec L1: h1 = silu(zW1 + x*Wd1x) -> h1f (A-frag layout, kc=w slice)
    #pragma unroll
    for (int quad = 0; quad < 4; ++quad) {
      unsigned int pw[4];
      #pragma unroll
      for (int jj = 0; jj < 8; jj += 2) {
        const int k = 32*w + 8*quad + jj;
        const float sA = zw1[k]   + x0v*wx0sh[k]   + x1v*wx1sh[k];
        const float sB = zw1[k+1] + x0v*wx0sh[k+1] + x1v*wx1sh[k+1];
        pw[jj>>1] = packbf(sA*sigf(sA), sB*sigf(sB));
      }
      uint4 v4; v4.x = pw[0]; v4.y = pw[1]; v4.z = pw[2]; v4.w = pw[3];
      ((uint4*)h1f)[(w*4 + (lane>>4))*64 + quad*16 + (lane&15)] = v4;
    }
    __syncthreads();

    // fwd (MFMA): S2 = H1 @ Wd2 + bd2; emit tau (-> tauf) and ebw per row
    float ebw[4];
    {
      bh8 af[4];
      #pragma unroll
      for (int kc = 0; kc < 4; ++kc)
        af[kc] = ((const bh8*)h1f)[(kc*4 + w)*64 + lane];
      float da[4] = {0.f, 0.f, 0.f, 0.f};
      #pragma unroll 1
      for (int half = 0; half < 2; ++half) {
        const int h4 = half*4;
        fx4 acc[4];
        #pragma unroll
        for (int i = 0; i < 4; ++i) {
          const float bv = bd2sh[(h4+i)*16 + rr];
          acc[i] = (fx4){bv, bv, bv, bv};
        }
        #pragma unroll
        for (int i = 0; i < 4; ++i) {
          const int nt = h4 + i;
          const bh8 b0 = Wd2f[(0*8+nt)*64 + lane];
          const bh8 b1 = Wd2f[(1*8+nt)*64 + lane];
          const bh8 b2 = Wd2f[(2*8+nt)*64 + lane];
          const bh8 b3 = Wd2f[(3*8+nt)*64 + lane];
          acc[i] = __builtin_amdgcn_mfma_f32_16x16x32_bf16(af[0], b0, acc[i], 0,0,0);
          acc[i] = __builtin_amdgcn_mfma_f32_16x16x32_bf16(af[1], b1, acc[i], 0,0,0);
          acc[i] = __builtin_amdgcn_mfma_f32_16x16x32_bf16(af[2], b2, acc[i], 0,0,0);
          acc[i] = __builtin_amdgcn_mfma_f32_16x16x32_bf16(af[3], b3, acc[i], 0,0,0);
        }
        #pragma unroll
        for (int i = 0; i < 4; ++i) {
          const int nt = h4 + i;
          const float w3 = wd3sh[nt*16 + rr];
          #pragma unroll
          for (int g = 0; g < 4; ++g) {
            const float s2 = acc[i][g];
            const float sg = sigf(s2);
            da[g] = fmaf(s2*sg, w3, da[g]);
            const unsigned int tb = bfb(w3 * (sg * fmaf(s2, 1.0f - sg, 1.0f)));
            const unsigned int pb = (unsigned int)__shfl_xor((int)tb, 1, 64);
            if ((rr & 1) == 0) {
              const int unit = ((nt>>1)*4 + w)*64 + (2*(nt&1) + (rr>>3))*16 + 4*qq + g;
              tauf[unit*4 + ((rr&7)>>1)] = tb | (pb << 16);
            }
          }
        }
      }
      #pragma unroll
      for (int g = 0; g < 4; ++g) {
        float v = da[g];
        v += __shfl_xor(v, 1, 64);
        v += __shfl_xor(v, 2, 64);
        v += __shfl_xor(v, 4, 64);
        v += __shfl_xor(v, 8, 64);
        ebw[g] = t * mkq[g] * (v + bd3v - yq[g]);
      }
    }
    wave_sync();

    // bwd (MFMA): U = TAU @ Wd2^T; dsum[k] = colsum(ebw * silu'(s1) * U)
    {
      bh8 tf4[4];
      #pragma unroll
      for (int kc = 0; kc < 4; ++kc)
        tf4[kc] = ((const bh8*)tauf)[(kc*4 + w)*64 + lane];
      #pragma unroll 1
      for (int half = 0; half < 2; ++half) {
        const int h4 = half*4;
        fx4 u[4];
        #pragma unroll
        for (int i = 0; i < 4; ++i) u[i] = (fx4){0.f, 0.f, 0.f, 0.f};
        #pragma unroll
        for (int i = 0; i < 4; ++i) {
          const int nt = h4 + i;
          const bh8 b0 = Wd2Tf[(0*8+nt)*64 + lane];
          const bh8 b1 = Wd2Tf[(1*8+nt)*64 + lane];
          const bh8 b2 = Wd2Tf[(2*8+nt)*64 + lane];
          const bh8 b3 = Wd2Tf[(3*8+nt)*64 + lane];
          u[i] = __builtin_amdgcn_mfma_f32_16x16x32_bf16(tf4[0], b0, u[i], 0,0,0);
          u[i] = __builtin_amdgcn_mfma_f32_16x16x32_bf16(tf4[1], b1, u[i], 0,0,0);
          u[i] = __builtin_amdgcn_mfma_f32_16x16x32_bf16(tf4[2], b2, u[i], 0,0,0);
          u[i] = __builtin_amdgcn_mfma_f32_16x16x32_bf16(tf4[3], b3, u[i], 0,0,0);
        }
        #pragma unroll
        for (int i = 0; i < 4; ++i) {
          const int nt = h4 + i;
          const float zv = zw1[nt*16 + rr];
          const float wa = wx0sh[nt*16 + rr];
          const float wb = wx1sh[nt*16 + rr];
          float snt = 0.f;
          #pragma unroll
          for (int g = 0; g < 4; ++g) {
            const float s1 = zv + x0q[g]*wa + x1q[g]*wb;
            const float sg = sigf(s1);
            snt += ebw[g] * (sg * fmaf(s1, 1.0f - sg, 1.0f)) * u[i][g];
          }
          snt += __shfl_xor(snt, 16, 64);
          snt += __shfl_xor(snt, 32, 64);
          if (lane < 16) dsumP[w*128 + nt*16 + lane] = snt;
        }
      }
    }
    __syncthreads();

    // dsum combine + drift f1
    if (tid < 128) {
      dsumC[tid] = dsumP[tid] + dsumP[128+tid] + dsumP[256+tid] + dsumP[384+tid];
      float p0 = fmaf(t, Wf1[192*HD + tid], bf1[tid]);
      float p1 = 0.f, p2 = 0.f, p3 = 0.f;
      #pragma unroll 4
      for (int j = 0; j < 64; j += 4) {
        p0 = fmaf(zsh[j+0], Wf1[(j+0)*HD + tid], p0);
        p1 = fmaf(zsh[j+1], Wf1[(j+1)*HD + tid], p1);
        p2 = fmaf(zsh[j+2], Wf1[(j+2)*HD + tid], p2);
        p3 = fmaf(zsh[j+3], Wf1[(j+3)*HD + tid], p3);
      }
      #pragma unroll 4
      for (int j = 0; j < 128; j += 4) {
        p0 = fmaf(rsh[j+0], Wf1[(64+j+0)*HD + tid], p0);
        p1 = fmaf(rsh[j+1], Wf1[(64+j+1)*HD + tid], p1);
        p2 = fmaf(rsh[j+2], Wf1[(64+j+2)*HD + tid], p2);
        p3 = fmaf(rsh[j+3], Wf1[(64+j+3)*HD + tid], p3);
      }
      const float a = (p0+p1) + (p2+p3);
      f1sh[tid] = a * sigf(a);
    }
    __syncthreads();
    if (tid < 128) {
      float p0 = bf2[tid], p1 = 0.f, p2 = 0.f, p3 = 0.f;
      #pragma unroll 4
      for (int j = 0; j < 128; j += 4) {
        p0 = fmaf(f1sh[j+0], Wf2[(j+0)*HD + tid], p0);
        p1 = fmaf(f1sh[j+1], Wf2[(j+1)*HD + tid], p1);
        p2 = fmaf(f1sh[j+2], Wf2[(j+2)*HD + tid], p2);
        p3 = fmaf(f1sh[j+3], Wf2[(j+3)*HD + tid], p3);
      }
      const float a = (p0+p1) + (p2+p3);
      f2sh[tid] = a * sigf(a);
    }
    __syncthreads();
    if (tid < 128) {
      if (tid < 64) {
        float p0 = bf3[tid], p1 = 0.f, p2 = 0.f, p3 = 0.f;
        #pragma unroll 4
        for (int h = 0; h < 128; h += 4) {
          p0 = fmaf(f2sh[h+0], Wf3[(h+0)*ZD + tid], p0);
          p1 = fmaf(f2sh[h+1], Wf3[(h+1)*ZD + tid], p1);
          p2 = fmaf(f2sh[h+2], Wf3[(h+2)*ZD + tid], p2);
          p3 = fmaf(f2sh[h+3], Wf3[(h+3)*ZD + tid], p3);
        }
        bgz[tid] = (p0+p1) + (p2+p3);              // drift output b_j
      } else {
        const int j = tid - 64;
        float p0 = 0.f, p1 = 0.f, p2 = 0.f, p3 = 0.f;
        #pragma unroll 4
        for (int h = 0; h < 128; h += 4) {
          p0 = fmaf(dsumC[h+0], Wd1[j*HD + h+0], p0);
          p1 = fmaf(dsumC[h+1], Wd1[j*HD + h+1], p1);
          p2 = fmaf(dsumC[h+2], Wd1[j*HD + h+2], p2);
          p3 = fmaf(dsumC[h+3], Wd1[j*HD + h+3], p3);
        }
        bgz[64 + j] = (p0+p1) + (p2+p3);           // gz_j (t folded into ebw)
      }
    }
    __syncthreads();
    if (tid < 64) {
      const float zold = zsh[tid];
      float g = zold + bgz[64 + tid];
      g = fminf(fmaxf(g, -100.0f), 100.0f);
      zsh[tid] = zold + (bgz[tid] - g) * dt
               + dco * noises[(size_t)st * (B_TOT * ZD) + b * ZD + tid];
    }
    __syncthreads();
  }

  if (tid < 64) out[b * ZD + tid] = zsh[tid];
}

extern "C" void kernel_launch(void* const* d_in, const int* in_sizes, int n_in,
                              void* d_out, int out_size, void* d_ws, size_t ws_size,
                              hipStream_t stream) {
  const float* x_ctx  = (const float*)d_in[0];
  const float* y_ctx  = (const float*)d_in[1];
  const float* mask   = (const float*)d_in[2];
  const float* z0     = (const float*)d_in[3];
  const float* noises = (const float*)d_in[4];
  const float* We1 = (const float*)d_in[5];  const float* be1 = (const float*)d_in[6];
  const float* We2 = (const float*)d_in[7];  const float* be2 = (const float*)d_in[8];
  const float* We3 = (const float*)d_in[9];  const float* be3 = (const float*)d_in[10];
  const float* Wd1 = (const float*)d_in[11]; const float* bd1 = (const float*)d_in[12];
  const float* Wd2 = (const float*)d_in[13]; const float* bd2 = (const float*)d_in[14];
  const float* Wd3 = (const float*)d_in[15]; const float* bd3 = (const float*)d_in[16];
  const float* Wf1 = (const float*)d_in[17]; const float* bf1 = (const float*)d_in[18];
  const float* Wf2 = (const float*)d_in[19]; const float* bf2 = (const float*)d_in[20];
  const float* Wf3 = (const float*)d_in[21]; const float* bf3 = (const float*)d_in[22];

  const int steps = in_sizes[4] / (B_TOT * ZD);
  const float dt  = 1.0f / (float)steps;
  const float dco = (float)sqrt(2.0 / (double)steps);

  ushort* wsu = (ushort*)d_ws;   // 4 bf16 frag arrays, 128 KB total

  hipLaunchKernelGGL(prep_kernel, dim3(256), dim3(256), 0, stream, Wd2, We2, We3, wsu);
  hipLaunchKernelGGL(metanets_kernel, dim3(B_TOT), dim3(256), 0, stream,
      x_ctx, y_ctx, mask, z0, noises,
      We1, be1, be2, be3,
      Wd1, bd1, bd2, Wd3, bd3,
      Wf1, bf1, Wf2, bf2, Wf3, bf3,
      wsu, (float*)d_out, steps, dt, dco);
}